// Round 1
// baseline (111.109 us; speedup 1.0000x reference)
//
#include <hip/hip_runtime.h>
#include <stdint.h>
#include <stddef.h>

// BalancedFocalLoss fused kernel — MI355X (gfx950)
//
// Math reduction:
//   z = concat(zx, zy); zn = z/||z||;  sim = zn·znT / 0.5
//   ce_i  = log( sum_{j != i} exp(sim_ij) ) - sim_{i,(i+B)%N}
//   out   = mean( ALPHA * (1-exp(-ce))^2 * ce )
// We store s2n = sqrt(2)*zn in bf16 so that s2n_i · s2n_j == sim_ij directly.
// sim in [-2,2] => exp-sum needs no running max.  sim symmetric => any MFMA
// C-layout transpose is harmless (row sums == col sums).

typedef __attribute__((ext_vector_type(8))) short short8;
typedef __attribute__((ext_vector_type(4))) float f32x4;

#define NROWS 8192
#define DDIM 256

__device__ __forceinline__ unsigned short f2bf(float f) {
  unsigned int u = __float_as_uint(f);
  u = (u + 0x7FFFu + ((u >> 16) & 1u)) >> 16;   // RNE, inputs finite
  return (unsigned short)u;
}
__device__ __forceinline__ float bf2f(unsigned short s) {
  return __uint_as_float(((unsigned int)s) << 16);
}

// ---------------- 1. row normalize + sqrt(2) scale + bf16 cast ----------------
__global__ __launch_bounds__(64) void norm_kernel(const float* __restrict__ zx,
                                                  const float* __restrict__ zy,
                                                  unsigned short* __restrict__ zn) {
  const int row = blockIdx.x;       // 8192
  const int lane = threadIdx.x;     // 64 lanes, 4 floats each
  const float* src = (row < 4096) ? (zx + (size_t)row * DDIM)
                                  : (zy + (size_t)(row - 4096) * DDIM);
  float4 v = reinterpret_cast<const float4*>(src)[lane];
  float ss = v.x * v.x + v.y * v.y + v.z * v.z + v.w * v.w;
#pragma unroll
  for (int m = 1; m < 64; m <<= 1) ss += __shfl_xor(ss, m);
  const float sc = 1.41421356237f * rsqrtf(ss);   // sqrt(2)/||z||
  ushort4 o;
  o.x = f2bf(v.x * sc); o.y = f2bf(v.y * sc);
  o.z = f2bf(v.z * sc); o.w = f2bf(v.w * sc);
  reinterpret_cast<ushort4*>(zn + (size_t)row * DDIM)[lane] = o;
}

// ---------------- 2. positive-pair similarities: pos[b] = s2n_b · s2n_{b+4096} ----------------
__global__ __launch_bounds__(64) void pos_kernel(const unsigned short* __restrict__ zn,
                                                 float* __restrict__ pos) {
  const int b = blockIdx.x;        // 4096
  const int lane = threadIdx.x;
  ushort4 a = reinterpret_cast<const ushort4*>(zn + (size_t)b * DDIM)[lane];
  ushort4 c = reinterpret_cast<const ushort4*>(zn + (size_t)(b + 4096) * DDIM)[lane];
  float s = bf2f(a.x) * bf2f(c.x) + bf2f(a.y) * bf2f(c.y) +
            bf2f(a.z) * bf2f(c.z) + bf2f(a.w) * bf2f(c.w);
#pragma unroll
  for (int m = 1; m < 64; m <<= 1) s += __shfl_xor(s, m);
  if (lane == 0) pos[b] = s;
}

// ---------------- 3. fused sim GEMM + exp row-sum ----------------
// grid 512 = 64 row-panels x 8 col-chunks.  Block: 256 thr (4 waves, 2x2),
// tile 128x128, wave tile 64x64 (4x4 frags of 16x16x32 bf16 MFMA), BK=64,
// double-buffered LDS (64 KiB) staged via global_load_lds width-16.
__global__ __launch_bounds__(256, 2) void simexp_kernel(const unsigned short* __restrict__ zn,
                                                        float* __restrict__ partial) {
  __shared__ unsigned short smem[2][2][128 * 64];
  const int bid = blockIdx.x;
  const int panel = bid >> 3;
  const int chunk = bid & 7;
  const int R0 = panel << 7;            // row base
  const int tid = threadIdx.x;
  const int lane = tid & 63;
  const int wid = tid >> 6;
  const int wr = wid >> 1;              // wave row (0/1)
  const int wc = wid & 1;               // wave col (0/1)

  const f32x4 z4 = {0.f, 0.f, 0.f, 0.f};
  f32x4 acc[4][4];
  float rsum[4][4];
#pragma unroll
  for (int m = 0; m < 4; ++m)
#pragma unroll
    for (int n = 0; n < 4; ++n) { acc[m][n] = z4; rsum[m][n] = 0.f; }

  auto stage = [&](int buf, int which, int row0, int k0) {
    // 128 rows x 64 k, row-major; 16384 B = 1024 x 16B units.
    unsigned short* lb = &smem[buf][which][0];
#pragma unroll
    for (int j = 0; j < 4; ++j) {
      const int u = j * 256 + wid * 64 + lane;                 // this lane's unit
      const unsigned short* g = zn + (size_t)(row0 + (u >> 3)) * DDIM + k0 + (u & 7) * 8;
      unsigned short* l = lb + (size_t)(j * 256 + wid * 64) * 8; // wave-uniform base; HW adds lane*16
      __builtin_amdgcn_global_load_lds(
          (const __attribute__((address_space(1))) void*)g,
          (__attribute__((address_space(3))) void*)l, 16, 0, 0);
    }
  };

  stage(0, 0, R0, 0);
  stage(0, 1, chunk * 1024, 0);
  __syncthreads();

  int buf = 0;
  for (int t = 0; t < 8; ++t) {
    for (int kk = 0; kk < 4; ++kk) {
      int nt = t, nkk = kk + 1;
      if (nkk == 4) { nt = t + 1; nkk = 0; }
      if (nt < 8) {
        stage(buf ^ 1, 0, R0, nkk * 64);
        stage(buf ^ 1, 1, chunk * 1024 + nt * 128, nkk * 64);
      }
      const unsigned short* A = &smem[buf][0][0];
      const unsigned short* Bm = &smem[buf][1][0];
#pragma unroll
      for (int ks = 0; ks < 2; ++ks) {
        short8 af[4], bfr[4];
#pragma unroll
        for (int m = 0; m < 4; ++m)
          af[m] = *reinterpret_cast<const short8*>(
              A + ((wr * 64 + m * 16 + (lane & 15)) * 64 + ks * 32 + (lane >> 4) * 8));
#pragma unroll
        for (int n = 0; n < 4; ++n)
          bfr[n] = *reinterpret_cast<const short8*>(
              Bm + ((wc * 64 + n * 16 + (lane & 15)) * 64 + ks * 32 + (lane >> 4) * 8));
#pragma unroll
        for (int m = 0; m < 4; ++m)
#pragma unroll
          for (int n = 0; n < 4; ++n)
            acc[m][n] = __builtin_amdgcn_mfma_f32_16x16x32_bf16(af[m], bfr[n], acc[m][n], 0, 0, 0);
      }
      buf ^= 1;
      __syncthreads();
    }
    // epilogue for tile t: exp + diagonal-exclude + per-row accumulate
    const int C0 = chunk * 1024 + t * 128;
#pragma unroll
    for (int m = 0; m < 4; ++m) {
      const int grow_b = R0 + wr * 64 + m * 16 + ((lane >> 4) << 2);
#pragma unroll
      for (int n = 0; n < 4; ++n) {
        const int gcol = C0 + wc * 64 + n * 16 + (lane & 15);
#pragma unroll
        for (int r = 0; r < 4; ++r) {
          const float e = __expf(acc[m][n][r]);
          rsum[m][r] += ((grow_b + r) == gcol) ? 0.f : e;
        }
        acc[m][n] = z4;
      }
    }
  }

  // reduce exp-sums across the 16 lanes (cols) of each group, store partials
#pragma unroll
  for (int m = 0; m < 4; ++m)
#pragma unroll
    for (int r = 0; r < 4; ++r) {
      float s = rsum[m][r];
      s += __shfl_xor(s, 1); s += __shfl_xor(s, 2);
      s += __shfl_xor(s, 4); s += __shfl_xor(s, 8);
      if ((lane & 15) == 0) {
        const int grow = R0 + wr * 64 + m * 16 + ((lane >> 4) << 2) + r;
        partial[(size_t)(chunk * 2 + wc) * NROWS + grow] = s;
      }
    }
}

// ---------------- 4. per-row loss + reduction ----------------
__global__ __launch_bounds__(256) void d1_kernel(const float* __restrict__ partial,
                                                 const float* __restrict__ pos,
                                                 float* __restrict__ bsum) {
  const int row = blockIdx.x * 256 + threadIdx.x;   // 32 blocks x 256
  float s = 0.f;
#pragma unroll
  for (int c = 0; c < 16; ++c) s += partial[(size_t)c * NROWS + row];
  const float ce = __logf(s) - pos[row & 4095];
  const float pt = __expf(-ce);
  float f = (1.f - pt) * (1.f - pt) * ce;
#pragma unroll
  for (int m = 1; m < 64; m <<= 1) f += __shfl_xor(f, m);
  __shared__ float wsum[4];
  if ((threadIdx.x & 63) == 0) wsum[threadIdx.x >> 6] = f;
  __syncthreads();
  if (threadIdx.x == 0) bsum[blockIdx.x] = wsum[0] + wsum[1] + wsum[2] + wsum[3];
}

__global__ __launch_bounds__(64) void d2_kernel(const float* __restrict__ bsum,
                                                float* __restrict__ out) {
  const int l = threadIdx.x;
  float v = (l < 32) ? bsum[l] : 0.f;
#pragma unroll
  for (int m = 1; m < 64; m <<= 1) v += __shfl_xor(v, m);
  if (l == 0) out[0] = 0.25f * v / 8192.f;   // ALPHA * mean
}

extern "C" void kernel_launch(void* const* d_in, const int* in_sizes, int n_in,
                              void* d_out, int out_size, void* d_ws, size_t ws_size,
                              hipStream_t stream) {
  const float* zx = (const float*)d_in[0];
  const float* zy = (const float*)d_in[1];
  float* out = (float*)d_out;

  // workspace layout (~4.7 MiB): zn bf16 | pos | partial | bsum
  unsigned short* zn = (unsigned short*)d_ws;                          // 8192*256*2 = 4 MiB
  float* pos = (float*)((char*)d_ws + (size_t)NROWS * DDIM * 2);       // 16 KiB
  float* partial = pos + 4096;                                         // 16*8192*4 = 512 KiB
  float* bsum = partial + 16 * NROWS;                                  // 128 B

  norm_kernel<<<NROWS, 64, 0, stream>>>(zx, zy, zn);
  pos_kernel<<<4096, 64, 0, stream>>>(zn, pos);
  simexp_kernel<<<512, 256, 0, stream>>>(zn, partial);
  d1_kernel<<<32, 256, 0, stream>>>(partial, pos, bsum);
  d2_kernel<<<1, 64, 0, stream>>>(bsum, out);
}